// Round 7
// baseline (1076.549 us; speedup 1.0000x reference)
//
#include <hip/hip_runtime.h>
#include <stdint.h>

// ---------------- problem constants ----------------
#define E_NUM 600000
#define N_NODES 60000
#define NPER 20000
#define NKEY 300000          // dst*5+rel keys
#define MROW 60032           // 469*128 rows covered by N-sized GEMMs
#define HPAD 60160           // h/Abuf row capacity (encoders write up to 60095)
#define MP20 20096           // 157*128
#define KA 1536              // fused A width: [h | U0..U4]

typedef __attribute__((ext_vector_type(8))) short frag8;   // 8 bf16
typedef __attribute__((ext_vector_type(4))) float facc4;   // 4 f32 acc

__device__ __forceinline__ float bf2f(uint16_t u) {
  union { uint32_t i; float f; } v; v.i = ((uint32_t)u) << 16; return v.f;
}
__device__ __forceinline__ uint16_t f2bf(float f) {
  union { float f; uint32_t i; } v; v.f = f;
  uint32_t r = v.i + 0x7FFFu + ((v.i >> 16) & 1u);
  return (uint16_t)(r >> 16);
}
// dual-dtype input read: mode==0 -> bf16, mode==1 -> f32
__device__ __forceinline__ uint16_t in2bf(const void* p, size_t i, int mode) {
  return mode ? f2bf(((const float*)p)[i]) : ((const uint16_t*)p)[i];
}

typedef __attribute__((address_space(3))) uint32_t lds_u32;
typedef const __attribute__((address_space(1))) uint32_t glb_u32;
__device__ __forceinline__ void gl_lds16(const uint16_t* g, uint16_t* l) {
  // async global->LDS, 16B/lane; LDS dest = wave-uniform base + lane*16
  __builtin_amdgcn_global_load_lds((glb_u32*)g, (lds_u32*)l, 16, 0, 0);
}

// ---------------- MFMA GEMM: C[M,N] = A @ Bt^T (+bias, opt lrelu) -----------
// A row-major [M,lda] bf16 (reads K cols), Bt row-major [N,ldb] bf16.
// BM=BN=128, BK=32; 256 thr = 4 waves 2x2 of 64x64. K % 32 == 0.
// Staging via global_load_lds width=16 (m97 structure).
template<int ACT>
__global__ __launch_bounds__(256)
void gemm_bt(const uint16_t* __restrict__ A, int lda,
             const uint16_t* __restrict__ Bt, int ldb,
             const uint16_t* __restrict__ bias, uint16_t* __restrict__ C,
             int N, int K)
{
  __shared__ __align__(16) uint16_t sA[128 * 32];
  __shared__ __align__(16) uint16_t sB[128 * 32];
  const int tid = threadIdx.x;
  const int lane = tid & 63;
  const size_t mbase = (size_t)blockIdx.x * 128;
  const size_t nbase = (size_t)blockIdx.y * 128;
  const int wave = tid >> 6;
  const int wm = (wave >> 1) * 64;
  const int wn = (wave & 1) * 64;

  const uint16_t* Ab = A + mbase * lda;
  const uint16_t* Bb = Bt + nbase * ldb;

  facc4 acc[4][4] = {};

  const int nk = K >> 5;
  for (int kt = 0; kt < nk; ++kt) {
    const int kb = kt << 5;
#pragma unroll
    for (int it = 0; it < 2; ++it) {
      const int c = it * 256 + tid;          // chunk id 0..511, 16B each
      const int r = c >> 2;                  // tile row ([128][32] tiles)
      const int kc = (c & 3) * 8;            // k offset within tile row
      // lane's chunk lands at LDS elem (it*256+wave*64)*8 + lane*8 == c*8
      gl_lds16(Ab + (size_t)r * lda + kb + kc, sA + (size_t)(it * 256 + wave * 64) * 8);
      gl_lds16(Bb + (size_t)r * ldb + kb + kc, sB + (size_t)(it * 256 + wave * 64) * 8);
    }
    __syncthreads();   // compiler drains vmcnt(0) before s_barrier
    {
      const int m15 = lane & 15, q8 = (lane >> 4) * 8;
      frag8 af[4], bfr[4];
#pragma unroll
      for (int i = 0; i < 4; ++i)
        af[i] = *(const frag8*)(sA + (size_t)(wm + i * 16 + m15) * 32 + q8);
#pragma unroll
      for (int j = 0; j < 4; ++j)
        bfr[j] = *(const frag8*)(sB + (size_t)(wn + j * 16 + m15) * 32 + q8);
#pragma unroll
      for (int i = 0; i < 4; ++i)
#pragma unroll
        for (int j = 0; j < 4; ++j)
          acc[i][j] = __builtin_amdgcn_mfma_f32_16x16x32_bf16(af[i], bfr[j], acc[i][j], 0, 0, 0);
    }
    __syncthreads();
  }

  // epilogue: C/D layout col=lane&15, row=(lane>>4)*4+reg
  const int m15 = lane & 15;
  const int r4 = (lane >> 4) * 4;
#pragma unroll
  for (int j = 0; j < 4; ++j) {
    const size_t col = nbase + wn + j * 16 + m15;
    const float bv = bias ? bf2f(bias[col]) : 0.f;
#pragma unroll
    for (int i = 0; i < 4; ++i) {
      const size_t row0 = mbase + wm + i * 16 + r4;
#pragma unroll
      for (int r = 0; r < 4; ++r) {
        float v = acc[i][j][r] + bv;
        if (ACT) v = v > 0.f ? v : 0.3f * v;
        C[(row0 + r) * (size_t)N + col] = f2bf(v);
      }
    }
  }
}

// ---------------- small-N GEMM (N=16): out = A[M,256] @ W[256,16] + b --------
// W and bias are bf16 (from ws arena). MODE 0: f32 out + bf16 [M,32] pad copy.
template<int MODE>
__global__ __launch_bounds__(256)
void gemv16_k(const uint16_t* __restrict__ A, const uint16_t* __restrict__ W,
              const uint16_t* __restrict__ bias, float* __restrict__ outf,
              uint16_t* __restrict__ padout)
{
  __shared__ float sW[256 * 16];
  for (int i = threadIdx.x; i < 4096; i += 256) sW[i] = bf2f(W[i]);
  __syncthreads();
  const int row = blockIdx.x * 16 + (threadIdx.x >> 4);
  const int col = threadIdx.x & 15;
  const uint16_t* ar = A + (size_t)row * 256;
  float acc = 0.f;
#pragma unroll
  for (int k = 0; k < 256; k += 8) {
    uint4 w4 = *(const uint4*)(ar + k);
    const uint16_t* pw = (const uint16_t*)&w4;
#pragma unroll
    for (int j = 0; j < 8; ++j) acc += bf2f(pw[j]) * sW[(k + j) * 16 + col];
  }
  acc += bf2f(bias[col]);
  outf[(size_t)row * 16 + col] = acc;
  if (MODE == 0) {
    padout[(size_t)row * 32 + col] = f2bf(acc);
    padout[(size_t)row * 32 + 16 + col] = 0;
  }
}

// ---------------- dtype probe: detect f32-vs-bf16 inputs --------------------
__global__ void probe_k(const uint16_t* __restrict__ f0, int* __restrict__ mode) {
  long i = (long)blockIdx.x * 256 + threadIdx.x;
  int bad = 0;
  for (; i < 2000000; i += (long)gridDim.x * 256)
    bad |= (((f0[i] >> 7) & 0xFFu) == 0xFFu);   // bf16 NaN/Inf pattern
  if (bad) atomicOr(mode, 1);
}

// ---------------- weight transpose/pad (dual dtype, strided dst) ------------
// dst[n*dstLd + dstOff + k] = (k<K) ? src[soff + k*N + n] : 0,  k in [0,Kp)
struct TDesc { const void* src; uint16_t* dst; long soff; int K, N, Kp, dstLd, dstOff; };
struct TPack { TDesc d[23]; int n; };

__global__ void transpose_k(TPack p, const int* __restrict__ modep) {
  const TDesc t = p.d[blockIdx.y];
  const int mode = *modep;
  const int total = t.N * t.Kp;
  for (int i = blockIdx.x * 256 + threadIdx.x; i < total; i += gridDim.x * 256) {
    const int n = i / t.Kp, k = i - n * t.Kp;
    t.dst[(size_t)n * t.dstLd + t.dstOff + k] =
        (k < t.K) ? in2bf(t.src, (size_t)(t.soff + (long)k * t.N + n), mode)
                  : (uint16_t)0;
  }
}

// ---------------- bias/smallW -> bf16 arena (dual dtype) --------------------
struct BDesc { const void* src; int n; int dstoff; };
struct BPack { BDesc d[16]; int n; };

__global__ void biasconv_k(BPack p, uint16_t* __restrict__ arena,
                           const int* __restrict__ modep) {
  const BDesc b = p.d[blockIdx.y];
  const int mode = *modep;
  for (int i = blockIdx.x * 256 + threadIdx.x; i < b.n; i += gridDim.x * 256)
    arena[b.dstoff + i] = in2bf(b.src, i, mode);
}

// ------- feature repack rows [row0, row0+rowsOut) with K zero-padding -------
__global__ void repack_k(const void* __restrict__ in, uint16_t* __restrict__ out,
                         int row0, int Mvalid, int Kin, int Kpad, int rowsOut,
                         const int* __restrict__ modep)
{
  const int mode = *modep;
  const int total = rowsOut * Kpad;
  for (int i = blockIdx.x * 256 + threadIdx.x; i < total; i += gridDim.x * 256) {
    const int m = i / Kpad, k = i - m * Kpad;
    const int sm = row0 + m;
    out[i] = (sm < Mvalid && k < Kin) ? in2bf(in, (size_t)sm * Kin + k, mode)
                                      : (uint16_t)0;
  }
}

__global__ void zfill_k(uint16_t* p, int n) {
  int i = blockIdx.x * 256 + threadIdx.x;
  if (i < n) p[i] = 0;
}

// ---------------- edge counting-sort by key = dst*5 + rel -------------------
__global__ void init_k(int* deg5, int* mode, float* lossAcc) {
  int i = blockIdx.x * 256 + threadIdx.x;
  if (i < NKEY) deg5[i] = 0;
  if (i == NKEY) { *mode = 0; *lossAcc = 0.f; }
}

__global__ void hist5_k(const int* __restrict__ dst, const int* __restrict__ ety,
                        int* __restrict__ deg5) {
  int e = blockIdx.x * 256 + threadIdx.x;
  if (e < E_NUM) atomicAdd(&deg5[dst[e] * 5 + ety[e]], 1);
}

__global__ __launch_bounds__(1024) void scan1_k(const int* __restrict__ deg,
                                                int* __restrict__ offs, int* __restrict__ bsum) {
  __shared__ int s[1024];
  const int i = blockIdx.x * 1024 + threadIdx.x;
  int v = (i < NKEY) ? deg[i] : 0;
  s[threadIdx.x] = v; __syncthreads();
  for (int d = 1; d < 1024; d <<= 1) {
    int x = (threadIdx.x >= d) ? s[threadIdx.x - d] : 0;
    __syncthreads();
    s[threadIdx.x] += x; __syncthreads();
  }
  if (i < NKEY) offs[i + 1] = s[threadIdx.x];
  if (threadIdx.x == 1023) bsum[blockIdx.x] = s[1023];
}

__global__ void scan2_k(int* bsum) {
  if (threadIdx.x == 0 && blockIdx.x == 0) {
    int run = 0;
    for (int b = 0; b < 293; ++b) { int t = bsum[b]; bsum[b] = run; run += t; }
  }
}

__global__ __launch_bounds__(1024) void scan3_k(const int* __restrict__ deg,
                                                int* __restrict__ offs, int* __restrict__ cursor,
                                                const int* __restrict__ bsum) {
  const int i = blockIdx.x * 1024 + threadIdx.x;
  if (i >= NKEY) return;
  const int t = offs[i + 1] + bsum[blockIdx.x];
  offs[i + 1] = t;
  cursor[i] = t - deg[i];
  if (i == 0) offs[0] = 0;
}

__global__ void scatter5_k(const int* __restrict__ src, const int* __restrict__ dst,
                           const int* __restrict__ ety, int* __restrict__ cursor,
                           int* __restrict__ payload) {
  int e = blockIdx.x * 256 + threadIdx.x;
  if (e >= E_NUM) return;
  int key = dst[e] * 5 + ety[e];
  int pos = atomicAdd(&cursor[key], 1);
  payload[pos] = src[e];   // src node id
}

// ------- fused gather: Abuf[node] = [ h[node] | U_0 | ... | U_4 ] -----------
// One wave per key (node,rel); extra wave range copies h / zeroes pad rows.
__global__ __launch_bounds__(256)
void gather_all_k(const uint16_t* __restrict__ h, const int* __restrict__ offs5,
                  const int* __restrict__ payload, uint16_t* __restrict__ Abuf)
{
  const int w = blockIdx.x * 4 + (threadIdx.x >> 6);
  const int lane = threadIdx.x & 63;
  if (w < NKEY) {
    const int node = w / 5, rel = w - node * 5;
    const int o0 = offs5[w], o1 = offs5[w + 1];
    float a0 = 0.f, a1 = 0.f, a2 = 0.f, a3 = 0.f;
    for (int e = o0; e < o1; ++e) {
      const int s = payload[e];
      uint64_t v = *(const uint64_t*)(h + (size_t)s * 256 + lane * 4);
      a0 += bf2f((uint16_t)v);         a1 += bf2f((uint16_t)(v >> 16));
      a2 += bf2f((uint16_t)(v >> 32)); a3 += bf2f((uint16_t)(v >> 48));
    }
    uint64_t o = (uint64_t)f2bf(a0) | ((uint64_t)f2bf(a1) << 16)
               | ((uint64_t)f2bf(a2) << 32) | ((uint64_t)f2bf(a3) << 48);
    *(uint64_t*)(Abuf + (size_t)node * KA + (size_t)(1 + rel) * 256 + lane * 4) = o;
  } else {
    const int row = w - NKEY;
    if (row >= HPAD) return;
    uint16_t* arow = Abuf + (size_t)row * KA + lane * 4;
    if (row < N_NODES) {
      *(uint64_t*)arow = *(const uint64_t*)(h + (size_t)row * 256 + lane * 4);
    } else {
#pragma unroll
      for (int b = 0; b < 6; ++b) *(uint64_t*)(arow + b * 256) = 0;
    }
  }
}

__global__ void sentinel_k(uint16_t* out, float code) {
  int i = blockIdx.x * 256 + threadIdx.x;
  if (i > 320000) return;
  out[i] = (i == 0) ? f2bf(code) : (uint16_t)0;
}

// ---------------- outputs ---------------------------------------------------
__global__ __launch_bounds__(256) void loss_k(const float* __restrict__ cf,
                                              const float* __restrict__ feat,
                                              float* __restrict__ acc) {
  __shared__ float s[256];
  float p = 0.f;
  for (int i = blockIdx.x * 256 + threadIdx.x; i < N_NODES * 16; i += gridDim.x * 256) {
    float d = cf[i] - feat[i];
    p += d * d;
  }
  s[threadIdx.x] = p; __syncthreads();
  for (int d = 128; d > 0; d >>= 1) {
    if (threadIdx.x < d) s[threadIdx.x] += s[threadIdx.x + d];
    __syncthreads();
  }
  if (threadIdx.x == 0) atomicAdd(acc, s[0]);
}

// writes ALL 320001 outputs in the detected output dtype.
__global__ void final_k(const float* __restrict__ cf, const float* __restrict__ lossAcc,
                        const int* __restrict__ modep, void* __restrict__ outv)
{
  int i = blockIdx.x * 256 + threadIdx.x;
  if (i > 320000) return;
  float v = (i == 320000) ? *lossAcc * (1.f / 960000.f)
                          : (cf[i] + cf[i + 320000] + cf[i + 640000]) * (1.f / 3.f);
  if (*modep) ((float*)outv)[i] = v;
  else ((uint16_t*)outv)[i] = f2bf(v);
}

// ---------------- host driver -----------------------------------------------
extern "C" void kernel_launch(void* const* d_in, const int* in_sizes, int n_in,
                              void* d_out, int out_size, void* d_ws, size_t ws_size,
                              hipStream_t stream)
{
  (void)in_sizes; (void)n_in; (void)out_size;
  const void* feat0 = d_in[0];
  const void* feat1 = d_in[1];
  const void* feat2 = d_in[2];
  const int* srcI = (const int*)d_in[3];
  const int* dstI = (const int*)d_in[4];
  const int* etyI = (const int*)d_in[5];
  const void *e0w1 = d_in[6],  *e0b1 = d_in[7],  *e0w2 = d_in[8],  *e0b2 = d_in[9];
  const void *e1w1 = d_in[10], *e1b1 = d_in[11], *e1w2 = d_in[12], *e1b2 = d_in[13];
  const void *e2w1 = d_in[14], *e2b1 = d_in[15], *e2w2 = d_in[16], *e2b2 = d_in[17];
  const void *e2w3 = d_in[18], *e2b3 = d_in[19];
  const void *gW = d_in[20], *gL = d_in[21], *gB = d_in[22];
  const void *dw1 = d_in[23], *db1 = d_in[24], *dw2 = d_in[25], *db2 = d_in[26];
  const void *cew1 = d_in[27], *ceb1 = d_in[28], *cew2 = d_in[29], *ceb2 = d_in[30];
  const void *cdw1 = d_in[31], *cdb1 = d_in[32], *cdw2 = d_in[33], *cdb2 = d_in[34];

  uint8_t* base = (uint8_t*)d_ws;
  size_t off = 0;
  auto alloc = [&](size_t bytes) -> void* {
    void* p = base + off;
    off += (bytes + 255) & ~(size_t)255;
    return p;
  };
  int* modep    = (int*)alloc(4);
  int* bsum     = (int*)alloc(512 * 4);
  float* lossAcc = (float*)alloc(4);
  int* deg5    = (int*)alloc((size_t)NKEY * 4);
  int* offs5   = (int*)alloc((size_t)(NKEY + 33) * 4);
  int* cursor5 = (int*)alloc((size_t)NKEY * 4);
  int* payload = (int*)alloc((size_t)E_NUM * 4);
  auto wal = [&](size_t elems) { return (uint16_t*)alloc(elems * 2); };
  uint16_t* arena = wal(12576);          // biases + dw2/cdw2, bf16
  uint16_t* e0w1t = wal(256 * 128);
  uint16_t* e0w2t = wal(256 * 256);
  uint16_t* e1w1t = wal(256 * 320);
  uint16_t* e1w2t = wal(256 * 256);
  uint16_t* e2w1t = wal(512 * 768);
  uint16_t* e2w2t = wal(256 * 512);
  uint16_t* e2w3t = wal(256 * 256);
  uint16_t* dw1t  = wal(256 * 256);
  uint16_t* cew1t = wal(1024 * 32);
  uint16_t* cew2t = wal(256 * 1024);
  uint16_t* cdw1t = wal(256 * 256);
  uint16_t* wall0 = wal(256 * KA);       // [gL0; W_0..W_4]^T  [256 rows][1536]
  uint16_t* wall1 = wal(256 * KA);
  uint16_t* h1 = wal((size_t)HPAD * 256);
  uint16_t* h2 = wal((size_t)HPAD * 256);
  uint16_t* Abuf = wal((size_t)HPAD * KA);   // 184.8 MB multi-use region

  if (off > ws_size) {   // loud failure if workspace too small
    float wsmb = (float)(ws_size >> 20);
    if (wsmb > 512.f) wsmb = 512.f;
    sentinel_k<<<dim3(1251), 256, 0, stream>>>((uint16_t*)d_out, 10000.f + 16.f * wsmb);
    return;
  }

  // bf16 arena offsets
  enum { oE0B1 = 0, oE0B2 = 256, oE1B1 = 512, oE1B2 = 768, oE2B1 = 1024,
         oE2B2 = 1536, oE2B3 = 1792, oGB = 2048, oDB1 = 2560, oDB2 = 2816,
         oCEB1 = 2832, oCEB2 = 3856, oCDB1 = 4112, oCDB2 = 4368,
         oDW2 = 4384, oCDW2 = 8480 };

  // overlays inside Abuf (phase-disjoint):
  uint16_t* f0p   = Abuf;                   // [20096,128]
  uint16_t* eTmp0 = Abuf + 2572288;         // [20096,256]
  uint16_t* f1p   = Abuf;                   // [20096,320]
  uint16_t* eTmp1 = Abuf + 6430720;         // [20096,256]
  uint16_t* f2p   = Abuf;                   // [20096,768]
  uint16_t* tEnc  = Abuf + 15433728;        // [20096,512]
  uint16_t* eEnc  = Abuf + 25722880;        // [20096,256]
  uint16_t* Hc      = Abuf;                            // [60032,1024] constr hidden
  uint16_t* featpad = Abuf + 61472768;                 // [60032,32]
  float*    featf   = (float*)(Abuf + 63393792);       // [60000,16] f32
  float*    cff     = (float*)(Abuf + 67233792);       // [60000,16] f32

  // --- init, dtype probe, edge counting-sort ---
  init_k<<<dim3(1173), 256, 0, stream>>>(deg5, modep, lossAcc);
  probe_k<<<dim3(512), 256, 0, stream>>>((const uint16_t*)feat0, modep);
  hist5_k<<<dim3(2344), 256, 0, stream>>>(dstI, etyI, deg5);
  scan1_k<<<dim3(293), 1024, 0, stream>>>(deg5, offs5, bsum);
  scan2_k<<<dim3(1), 64, 0, stream>>>(bsum);
  scan3_k<<<dim3(293), 1024, 0, stream>>>(deg5, offs5, cursor5, bsum);
  scatter5_k<<<dim3(2344), 256, 0, stream>>>(srcI, dstI, etyI, cursor5, payload);

  // --- bias / small-W conversion into bf16 arena ---
  BPack bp; int nb = 0;
  auto addB = [&](const void* s, int n, int dstoff) {
    bp.d[nb].src = s; bp.d[nb].n = n; bp.d[nb].dstoff = dstoff; ++nb;
  };
  addB(e0b1, 256, oE0B1); addB(e0b2, 256, oE0B2);
  addB(e1b1, 256, oE1B1); addB(e1b2, 256, oE1B2);
  addB(e2b1, 512, oE2B1); addB(e2b2, 256, oE2B2); addB(e2b3, 256, oE2B3);
  addB(gB, 512, oGB);
  addB(db1, 256, oDB1); addB(db2, 16, oDB2);
  addB(ceb1, 1024, oCEB1); addB(ceb2, 256, oCEB2);
  addB(cdb1, 256, oCDB1); addB(cdb2, 16, oCDB2);
  addB(dw2, 4096, oDW2); addB(cdw2, 4096, oCDW2);
  bp.n = nb;
  biasconv_k<<<dim3(16, nb), 256, 0, stream>>>(bp, arena, modep);

  // --- weight transposes (Bt layout [N][K], dual dtype) ---
  TPack tp; int nd = 0;
  auto addT = [&](const void* s, long soff, uint16_t* d, int K, int N, int Kp,
                  int dstLd, int dstOff) {
    tp.d[nd].src = s; tp.d[nd].soff = soff; tp.d[nd].dst = d;
    tp.d[nd].K = K; tp.d[nd].N = N; tp.d[nd].Kp = Kp;
    tp.d[nd].dstLd = dstLd; tp.d[nd].dstOff = dstOff; ++nd;
  };
  addT(e0w1, 0, e0w1t, 100, 256, 128, 128, 0);
  addT(e0w2, 0, e0w2t, 256, 256, 256, 256, 0);
  addT(e1w1, 0, e1w1t, 300, 256, 320, 320, 0);
  addT(e1w2, 0, e1w2t, 256, 256, 256, 256, 0);
  addT(e2w1, 0, e2w1t, 768, 512, 768, 768, 0);
  addT(e2w2, 0, e2w2t, 512, 256, 512, 512, 0);
  addT(e2w3, 0, e2w3t, 256, 256, 256, 256, 0);
  addT(dw1,  0, dw1t,  256, 256, 256, 256, 0);
  addT(cew1, 0, cew1t, 16, 1024, 32, 32, 0);
  addT(cew2, 0, cew2t, 1024, 256, 1024, 1024, 0);
  addT(cdw1, 0, cdw1t, 256, 256, 256, 256, 0);
  uint16_t* walls[2] = { wall0, wall1 };
  for (int l = 0; l < 2; ++l) {
    addT(gL, (long)l * 65536, walls[l], 256, 256, 256, KA, 0);
    for (int r = 0; r < 5; ++r)
      addT(gW, (long)(l * 5 + r) * 65536, walls[l], 256, 256, 256, KA, 256 + r * 256);
  }
  tp.n = nd;   // 23
  transpose_k<<<dim3(48, nd), 256, 0, stream>>>(tp, modep);

  // --- encoders -> h1 ---
  repack_k<<<dim3(2048), 256, 0, stream>>>(feat0, f0p, 0, NPER, 100, 128, MP20, modep);
  gemm_bt<1><<<dim3(157, 2), 256, 0, stream>>>(f0p, 128, e0w1t, 128, arena + oE0B1, eTmp0, 256, 128);
  gemm_bt<0><<<dim3(157, 2), 256, 0, stream>>>(eTmp0, 256, e0w2t, 256, arena + oE0B2, h1, 256, 256);
  repack_k<<<dim3(2048), 256, 0, stream>>>(feat1, f1p, 0, NPER, 300, 320, MP20, modep);
  gemm_bt<1><<<dim3(157, 2), 256, 0, stream>>>(f1p, 320, e1w1t, 320, arena + oE1B1, eTmp1, 256, 320);
  gemm_bt<0><<<dim3(157, 2), 256, 0, stream>>>(eTmp1, 256, e1w2t, 256, arena + oE1B2, h1 + (size_t)NPER * 256, 256, 256);
  repack_k<<<dim3(4096), 256, 0, stream>>>(feat2, f2p, 0, NPER, 768, 768, MP20, modep);
  gemm_bt<1><<<dim3(157, 4), 256, 0, stream>>>(f2p, 768, e2w1t, 768, arena + oE2B1, tEnc, 512, 768);
  gemm_bt<1><<<dim3(157, 2), 256, 0, stream>>>(tEnc, 512, e2w2t, 512, arena + oE2B2, eEnc, 256, 512);
  gemm_bt<0><<<dim3(157, 2), 256, 0, stream>>>(eEnc, 256, e2w3t, 256, arena + oE2B3,
                                               h1 + (size_t)2 * NPER * 256, 256, 256);

  // --- RelGraphConv layers: one gather + one K=1536 GEMM each ---
  uint16_t* hbuf[2] = { h1, h2 };
  for (int l = 0; l < 2; ++l) {
    uint16_t* hin  = hbuf[l & 1];
    uint16_t* hout = hbuf[(l + 1) & 1];
    gather_all_k<<<dim3(90040), 256, 0, stream>>>(hin, offs5, payload, Abuf);
    gemm_bt<0><<<dim3(469, 2), 256, 0, stream>>>(Abuf, KA, walls[l], KA,
                                                 arena + oGB + l * 256, hout, 256, KA);
  }

  // --- decoder: feat = lrelu(h1@dw1+db1)@dw2 + db2 ---
  gemm_bt<1><<<dim3(469, 2), 256, 0, stream>>>(h1, 256, dw1t, 256, arena + oDB1, h2, 256, 256);
  gemv16_k<0><<<dim3(3750), 256, 0, stream>>>(h2, arena + oDW2, arena + oDB2, featf, featpad);
  zfill_k<<<dim3(4), 256, 0, stream>>>(featpad + (size_t)N_NODES * 32, 32 * 32);

  // --- constr encoder: Hc = lrelu(featpad@cew1+ceb1); h1 = Hc@cew2 + ceb2 ---
  gemm_bt<1><<<dim3(469, 8), 256, 0, stream>>>(featpad, 32, cew1t, 32, arena + oCEB1, Hc, 1024, 32);
  gemm_bt<0><<<dim3(469, 2), 256, 0, stream>>>(Hc, 1024, cew2t, 1024, arena + oCEB2, h1, 256, 1024);

  // --- constr decoder ---
  gemm_bt<1><<<dim3(469, 2), 256, 0, stream>>>(h1, 256, cdw1t, 256, arena + oCDB1, h2, 256, 256);
  gemv16_k<1><<<dim3(3750), 256, 0, stream>>>(h2, arena + oCDW2, arena + oCDB2, cff, nullptr);

  // --- outputs ---
  loss_k<<<dim3(512), 256, 0, stream>>>(cff, featf, lossAcc);
  final_k<<<dim3(1251), 256, 0, stream>>>(cff, lossAcc, modep, d_out);
}

// Round 8
// 1024.439 us; speedup vs baseline: 1.0509x; 1.0509x over previous
//
#include <hip/hip_runtime.h>
#include <stdint.h>

// ---------------- problem constants ----------------
#define E_NUM 600000
#define N_NODES 60000
#define NPER 20000
#define NKEY 300000          // dst*5+rel keys
#define MROW 60032           // 469*128 rows covered by N-sized GEMMs
#define HPAD 60160           // h/Abuf row capacity (encoders write up to 60095)
#define MP20 20096           // 157*128
#define KA 1536              // fused A width: [h | U0..U4]

typedef __attribute__((ext_vector_type(8))) short frag8;   // 8 bf16
typedef __attribute__((ext_vector_type(4))) float facc4;   // 4 f32 acc

__device__ __forceinline__ float bf2f(uint16_t u) {
  union { uint32_t i; float f; } v; v.i = ((uint32_t)u) << 16; return v.f;
}
__device__ __forceinline__ uint16_t f2bf(float f) {
  union { float f; uint32_t i; } v; v.f = f;
  uint32_t r = v.i + 0x7FFFu + ((v.i >> 16) & 1u);
  return (uint16_t)(r >> 16);
}
// dual-dtype input read: mode==0 -> bf16, mode==1 -> f32
__device__ __forceinline__ uint16_t in2bf(const void* p, size_t i, int mode) {
  return mode ? f2bf(((const float*)p)[i]) : ((const uint16_t*)p)[i];
}

typedef __attribute__((address_space(3))) uint32_t lds_u32;
typedef const __attribute__((address_space(1))) uint32_t glb_u32;
__device__ __forceinline__ void gl_lds16(const uint16_t* g, uint16_t* l) {
  // async global->LDS, 16B/lane; LDS dest = wave-uniform base + lane*16
  __builtin_amdgcn_global_load_lds((glb_u32*)g, (lds_u32*)l, 16, 0, 0);
}

// ---------------- MFMA GEMM: C[M,N] = A @ Bt^T (+bias, opt lrelu) -----------
// A row-major [M,lda] bf16 (reads K cols), Bt row-major [N,ldb] bf16.
// BM=BN=128, BK=32; 256 thr = 4 waves 2x2 of 64x64. K % 32 == 0.
// Staging via global_load_lds width=16; LDS 16B-chunk XOR-swizzled by row&3
// to break the 4-way ds_read_b128 bank conflict (banks {0,16} only ->
// 4 bank-quads, 2-way residual which is free).
template<int ACT>
__global__ __launch_bounds__(256)
void gemm_bt(const uint16_t* __restrict__ A, int lda,
             const uint16_t* __restrict__ Bt, int ldb,
             const uint16_t* __restrict__ bias, uint16_t* __restrict__ C,
             int N, int K)
{
  __shared__ __align__(16) uint16_t sA[128 * 32];
  __shared__ __align__(16) uint16_t sB[128 * 32];
  const int tid = threadIdx.x;
  const int lane = tid & 63;
  const size_t mbase = (size_t)blockIdx.x * 128;
  const size_t nbase = (size_t)blockIdx.y * 128;
  const int wave = tid >> 6;
  const int wm = (wave >> 1) * 64;
  const int wn = (wave & 1) * 64;

  const uint16_t* Ab = A + mbase * lda;
  const uint16_t* Bb = Bt + nbase * ldb;

  facc4 acc[4][4] = {};

  const int nk = K >> 5;
  for (int kt = 0; kt < nk; ++kt) {
    const int kb = kt << 5;
#pragma unroll
    for (int it = 0; it < 2; ++it) {
      const int c = it * 256 + tid;              // phys chunk id 0..511, 16B
      const int r = c >> 2;                      // tile row
      const int kc = ((c & 3) ^ (r & 3)) * 8;    // swizzled logical k-chunk
      gl_lds16(Ab + (size_t)r * lda + kb + kc, sA + (size_t)(it * 256 + wave * 64) * 8);
      gl_lds16(Bb + (size_t)r * ldb + kb + kc, sB + (size_t)(it * 256 + wave * 64) * 8);
    }
    __syncthreads();   // compiler drains vmcnt(0) before s_barrier
    {
      const int m15 = lane & 15;
      const int q = lane >> 4;                   // logical k-chunk 0..3
      frag8 af[4], bfr[4];
#pragma unroll
      for (int i = 0; i < 4; ++i) {
        const int row = wm + i * 16 + m15;
        af[i] = *(const frag8*)(sA + (size_t)row * 32 + (q ^ (row & 3)) * 8);
      }
#pragma unroll
      for (int j = 0; j < 4; ++j) {
        const int row = wn + j * 16 + m15;
        bfr[j] = *(const frag8*)(sB + (size_t)row * 32 + (q ^ (row & 3)) * 8);
      }
#pragma unroll
      for (int i = 0; i < 4; ++i)
#pragma unroll
        for (int j = 0; j < 4; ++j)
          acc[i][j] = __builtin_amdgcn_mfma_f32_16x16x32_bf16(af[i], bfr[j], acc[i][j], 0, 0, 0);
    }
    __syncthreads();
  }

  // epilogue: C/D layout col=lane&15, row=(lane>>4)*4+reg
  const int m15 = lane & 15;
  const int r4 = (lane >> 4) * 4;
#pragma unroll
  for (int j = 0; j < 4; ++j) {
    const size_t col = nbase + wn + j * 16 + m15;
    const float bv = bias ? bf2f(bias[col]) : 0.f;
#pragma unroll
    for (int i = 0; i < 4; ++i) {
      const size_t row0 = mbase + wm + i * 16 + r4;
#pragma unroll
      for (int r = 0; r < 4; ++r) {
        float v = acc[i][j][r] + bv;
        if (ACT) v = v > 0.f ? v : 0.3f * v;
        C[(row0 + r) * (size_t)N + col] = f2bf(v);
      }
    }
  }
}

// ---------------- small-N GEMM (N=16): out = A[M,256] @ W[256,16] + b --------
// W and bias are bf16 (from ws arena). MODE 0: f32 out + bf16 [M,32] pad copy.
template<int MODE>
__global__ __launch_bounds__(256)
void gemv16_k(const uint16_t* __restrict__ A, const uint16_t* __restrict__ W,
              const uint16_t* __restrict__ bias, float* __restrict__ outf,
              uint16_t* __restrict__ padout)
{
  __shared__ float sW[256 * 16];
  for (int i = threadIdx.x; i < 4096; i += 256) sW[i] = bf2f(W[i]);
  __syncthreads();
  const int row = blockIdx.x * 16 + (threadIdx.x >> 4);
  const int col = threadIdx.x & 15;
  const uint16_t* ar = A + (size_t)row * 256;
  float acc = 0.f;
#pragma unroll
  for (int k = 0; k < 256; k += 8) {
    uint4 w4 = *(const uint4*)(ar + k);
    const uint16_t* pw = (const uint16_t*)&w4;
#pragma unroll
    for (int j = 0; j < 8; ++j) acc += bf2f(pw[j]) * sW[(k + j) * 16 + col];
  }
  acc += bf2f(bias[col]);
  outf[(size_t)row * 16 + col] = acc;
  if (MODE == 0) {
    padout[(size_t)row * 32 + col] = f2bf(acc);
    padout[(size_t)row * 32 + 16 + col] = 0;
  }
}

// ---------------- dtype probe: detect f32-vs-bf16 inputs --------------------
__global__ void probe_k(const uint16_t* __restrict__ f0, int* __restrict__ mode) {
  long i = (long)blockIdx.x * 256 + threadIdx.x;
  int bad = 0;
  for (; i < 2000000; i += (long)gridDim.x * 256)
    bad |= (((f0[i] >> 7) & 0xFFu) == 0xFFu);   // bf16 NaN/Inf pattern
  if (bad) atomicOr(mode, 1);
}

// ---------------- weight transpose/pad (dual dtype, strided dst) ------------
// dst[n*dstLd + dstOff + k] = (k<K) ? src[soff + k*N + n] : 0,  k in [0,Kp)
struct TDesc { const void* src; uint16_t* dst; long soff; int K, N, Kp, dstLd, dstOff; };
struct TPack { TDesc d[23]; int n; };

__global__ void transpose_k(TPack p, const int* __restrict__ modep) {
  const TDesc t = p.d[blockIdx.y];
  const int mode = *modep;
  const int total = t.N * t.Kp;
  for (int i = blockIdx.x * 256 + threadIdx.x; i < total; i += gridDim.x * 256) {
    const int n = i / t.Kp, k = i - n * t.Kp;
    t.dst[(size_t)n * t.dstLd + t.dstOff + k] =
        (k < t.K) ? in2bf(t.src, (size_t)(t.soff + (long)k * t.N + n), mode)
                  : (uint16_t)0;
  }
}

// ---------------- bias/smallW -> bf16 arena (dual dtype) --------------------
struct BDesc { const void* src; int n; int dstoff; };
struct BPack { BDesc d[16]; int n; };

__global__ void biasconv_k(BPack p, uint16_t* __restrict__ arena,
                           const int* __restrict__ modep) {
  const BDesc b = p.d[blockIdx.y];
  const int mode = *modep;
  for (int i = blockIdx.x * 256 + threadIdx.x; i < b.n; i += gridDim.x * 256)
    arena[b.dstoff + i] = in2bf(b.src, i, mode);
}

// ------- feature repack, 4-wide vectorized (Kin%4==0, Kpad%4==0) ------------
__global__ void repack4_k(const void* __restrict__ in, uint16_t* __restrict__ out,
                          int row0, int Mvalid, int Kin, int Kpad, int rowsOut,
                          const int* __restrict__ modep)
{
  const int mode = *modep;
  const int kq4 = Kpad >> 2;
  const int total = rowsOut * kq4;
  for (int idx = blockIdx.x * 256 + threadIdx.x; idx < total; idx += gridDim.x * 256) {
    const int m = idx / kq4;
    const int k = (idx - m * kq4) * 4;
    const int sm = row0 + m;
    uint64_t pack = 0;
    if (sm < Mvalid && k < Kin) {
      const size_t s = (size_t)sm * Kin + k;
      if (mode) {
        float4 f = *(const float4*)((const float*)in + s);
        pack = (uint64_t)f2bf(f.x) | ((uint64_t)f2bf(f.y) << 16)
             | ((uint64_t)f2bf(f.z) << 32) | ((uint64_t)f2bf(f.w) << 48);
      } else {
        pack = *(const uint64_t*)((const uint16_t*)in + s);
      }
    }
    *(uint64_t*)(out + (size_t)m * Kpad + k) = pack;
  }
}

__global__ void zfill_k(uint16_t* p, int n) {
  int i = blockIdx.x * 256 + threadIdx.x;
  if (i < n) p[i] = 0;
}

// ---------------- edge counting-sort by key = dst*5 + rel -------------------
__global__ void init_k(int* deg5, int* mode, float* lossAcc) {
  int i = blockIdx.x * 256 + threadIdx.x;
  if (i < NKEY) deg5[i] = 0;
  if (i == NKEY) { *mode = 0; *lossAcc = 0.f; }
}

__global__ void hist5_k(const int* __restrict__ dst, const int* __restrict__ ety,
                        int* __restrict__ deg5) {
  int e = blockIdx.x * 256 + threadIdx.x;
  if (e < E_NUM) atomicAdd(&deg5[dst[e] * 5 + ety[e]], 1);
}

__global__ __launch_bounds__(1024) void scan1_k(const int* __restrict__ deg,
                                                int* __restrict__ offs, int* __restrict__ bsum) {
  __shared__ int s[1024];
  const int i = blockIdx.x * 1024 + threadIdx.x;
  int v = (i < NKEY) ? deg[i] : 0;
  s[threadIdx.x] = v; __syncthreads();
  for (int d = 1; d < 1024; d <<= 1) {
    int x = (threadIdx.x >= d) ? s[threadIdx.x - d] : 0;
    __syncthreads();
    s[threadIdx.x] += x; __syncthreads();
  }
  if (i < NKEY) offs[i + 1] = s[threadIdx.x];
  if (threadIdx.x == 1023) bsum[blockIdx.x] = s[1023];
}

__global__ void scan2_k(int* bsum) {
  if (threadIdx.x == 0 && blockIdx.x == 0) {
    int run = 0;
    for (int b = 0; b < 293; ++b) { int t = bsum[b]; bsum[b] = run; run += t; }
  }
}

__global__ __launch_bounds__(1024) void scan3_k(const int* __restrict__ deg,
                                                int* __restrict__ offs, int* __restrict__ cursor,
                                                const int* __restrict__ bsum) {
  const int i = blockIdx.x * 1024 + threadIdx.x;
  if (i >= NKEY) return;
  const int t = offs[i + 1] + bsum[blockIdx.x];
  offs[i + 1] = t;
  cursor[i] = t - deg[i];
  if (i == 0) offs[0] = 0;
}

__global__ void scatter5_k(const int* __restrict__ src, const int* __restrict__ dst,
                           const int* __restrict__ ety, int* __restrict__ cursor,
                           int* __restrict__ payload) {
  int e = blockIdx.x * 256 + threadIdx.x;
  if (e >= E_NUM) return;
  int key = dst[e] * 5 + ety[e];
  int pos = atomicAdd(&cursor[key], 1);
  payload[pos] = src[e];   // src node id
}

// ------- fused gather: Abuf[node] = [ h[node] | U_0 | ... | U_4 ] -----------
// U_r = sum over in-edges of relation r of h[src]. One wave per node.
__global__ __launch_bounds__(256)
void gather_all_k(const uint16_t* __restrict__ h, const int* __restrict__ offs5,
                  const int* __restrict__ payload, uint16_t* __restrict__ Abuf)
{
  const int node = blockIdx.x * 4 + (threadIdx.x >> 6);
  const int lane = threadIdx.x & 63;
  uint16_t* arow = Abuf + (size_t)node * KA + lane * 4;
  if (node >= N_NODES) {
    if (node < HPAD) {
#pragma unroll
      for (int b = 0; b < 6; ++b) *(uint64_t*)(arow + b * 256) = 0;
    }
    return;
  }
  *(uint64_t*)arow = *(const uint64_t*)(h + (size_t)node * 256 + lane * 4);
  const int base = node * 5;
#pragma unroll
  for (int r = 0; r < 5; ++r) {
    const int o0 = offs5[base + r], o1 = offs5[base + r + 1];
    float a0 = 0.f, a1 = 0.f, a2 = 0.f, a3 = 0.f;
    for (int e = o0; e < o1; ++e) {
      const int s = payload[e];
      uint64_t v = *(const uint64_t*)(h + (size_t)s * 256 + lane * 4);
      a0 += bf2f((uint16_t)v);         a1 += bf2f((uint16_t)(v >> 16));
      a2 += bf2f((uint16_t)(v >> 32)); a3 += bf2f((uint16_t)(v >> 48));
    }
    uint64_t o = (uint64_t)f2bf(a0) | ((uint64_t)f2bf(a1) << 16)
               | ((uint64_t)f2bf(a2) << 32) | ((uint64_t)f2bf(a3) << 48);
    *(uint64_t*)(arow + (1 + r) * 256) = o;
  }
}

__global__ void sentinel_k(uint16_t* out, float code) {
  int i = blockIdx.x * 256 + threadIdx.x;
  if (i > 320000) return;
  out[i] = (i == 0) ? f2bf(code) : (uint16_t)0;
}

// ---------------- outputs ---------------------------------------------------
__global__ __launch_bounds__(256) void loss_k(const float* __restrict__ cf,
                                              const float* __restrict__ feat,
                                              float* __restrict__ acc) {
  __shared__ float s[256];
  float p = 0.f;
  for (int i = blockIdx.x * 256 + threadIdx.x; i < N_NODES * 16; i += gridDim.x * 256) {
    float d = cf[i] - feat[i];
    p += d * d;
  }
  s[threadIdx.x] = p; __syncthreads();
  for (int d = 128; d > 0; d >>= 1) {
    if (threadIdx.x < d) s[threadIdx.x] += s[threadIdx.x + d];
    __syncthreads();
  }
  if (threadIdx.x == 0) atomicAdd(acc, s[0]);
}

// writes ALL 320001 outputs in the detected output dtype.
__global__ void final_k(const float* __restrict__ cf, const float* __restrict__ lossAcc,
                        const int* __restrict__ modep, void* __restrict__ outv)
{
  int i = blockIdx.x * 256 + threadIdx.x;
  if (i > 320000) return;
  float v = (i == 320000) ? *lossAcc * (1.f / 960000.f)
                          : (cf[i] + cf[i + 320000] + cf[i + 640000]) * (1.f / 3.f);
  if (*modep) ((float*)outv)[i] = v;
  else ((uint16_t*)outv)[i] = f2bf(v);
}

// ---------------- host driver -----------------------------------------------
extern "C" void kernel_launch(void* const* d_in, const int* in_sizes, int n_in,
                              void* d_out, int out_size, void* d_ws, size_t ws_size,
                              hipStream_t stream)
{
  (void)in_sizes; (void)n_in; (void)out_size;
  const void* feat0 = d_in[0];
  const void* feat1 = d_in[1];
  const void* feat2 = d_in[2];
  const int* srcI = (const int*)d_in[3];
  const int* dstI = (const int*)d_in[4];
  const int* etyI = (const int*)d_in[5];
  const void *e0w1 = d_in[6],  *e0b1 = d_in[7],  *e0w2 = d_in[8],  *e0b2 = d_in[9];
  const void *e1w1 = d_in[10], *e1b1 = d_in[11], *e1w2 = d_in[12], *e1b2 = d_in[13];
  const void *e2w1 = d_in[14], *e2b1 = d_in[15], *e2w2 = d_in[16], *e2b2 = d_in[17];
  const void *e2w3 = d_in[18], *e2b3 = d_in[19];
  const void *gW = d_in[20], *gL = d_in[21], *gB = d_in[22];
  const void *dw1 = d_in[23], *db1 = d_in[24], *dw2 = d_in[25], *db2 = d_in[26];
  const void *cew1 = d_in[27], *ceb1 = d_in[28], *cew2 = d_in[29], *ceb2 = d_in[30];
  const void *cdw1 = d_in[31], *cdb1 = d_in[32], *cdw2 = d_in[33], *cdb2 = d_in[34];

  uint8_t* base = (uint8_t*)d_ws;
  size_t off = 0;
  auto alloc = [&](size_t bytes) -> void* {
    void* p = base + off;
    off += (bytes + 255) & ~(size_t)255;
    return p;
  };
  int* modep    = (int*)alloc(4);
  int* bsum     = (int*)alloc(512 * 4);
  float* lossAcc = (float*)alloc(4);
  int* deg5    = (int*)alloc((size_t)NKEY * 4);
  int* offs5   = (int*)alloc((size_t)(NKEY + 33) * 4);
  int* cursor5 = (int*)alloc((size_t)NKEY * 4);
  int* payload = (int*)alloc((size_t)E_NUM * 4);
  auto wal = [&](size_t elems) { return (uint16_t*)alloc(elems * 2); };
  uint16_t* arena = wal(12576);          // biases + dw2/cdw2, bf16
  uint16_t* e0w1t = wal(256 * 128);
  uint16_t* e0w2t = wal(256 * 256);
  uint16_t* e1w1t = wal(256 * 320);
  uint16_t* e1w2t = wal(256 * 256);
  uint16_t* e2w1t = wal(512 * 768);
  uint16_t* e2w2t = wal(256 * 512);
  uint16_t* e2w3t = wal(256 * 256);
  uint16_t* dw1t  = wal(256 * 256);
  uint16_t* cew1t = wal(1024 * 32);
  uint16_t* cew2t = wal(256 * 1024);
  uint16_t* cdw1t = wal(256 * 256);
  uint16_t* wall0 = wal(256 * KA);       // [gL0; W_0..W_4]^T  [256 rows][1536]
  uint16_t* wall1 = wal(256 * KA);
  uint16_t* h1 = wal((size_t)HPAD * 256);
  uint16_t* h2 = wal((size_t)HPAD * 256);
  uint16_t* Abuf = wal((size_t)HPAD * KA);   // 184.8 MB multi-use region

  if (off > ws_size) {   // loud failure if workspace too small
    float wsmb = (float)(ws_size >> 20);
    if (wsmb > 512.f) wsmb = 512.f;
    sentinel_k<<<dim3(1251), 256, 0, stream>>>((uint16_t*)d_out, 10000.f + 16.f * wsmb);
    return;
  }

  // bf16 arena offsets
  enum { oE0B1 = 0, oE0B2 = 256, oE1B1 = 512, oE1B2 = 768, oE2B1 = 1024,
         oE2B2 = 1536, oE2B3 = 1792, oGB = 2048, oDB1 = 2560, oDB2 = 2816,
         oCEB1 = 2832, oCEB2 = 3856, oCDB1 = 4112, oCDB2 = 4368,
         oDW2 = 4384, oCDW2 = 8480 };

  // overlays inside Abuf (phase-disjoint):
  uint16_t* f0p   = Abuf;                   // [20096,128]
  uint16_t* eTmp0 = Abuf + 2572288;         // [20096,256]
  uint16_t* f1p   = Abuf;                   // [20096,320]
  uint16_t* eTmp1 = Abuf + 6430720;         // [20096,256]
  uint16_t* f2p   = Abuf;                   // [20096,768]
  uint16_t* tEnc  = Abuf + 15433728;        // [20096,512]
  uint16_t* eEnc  = Abuf + 25722880;        // [20096,256]
  uint16_t* Hc      = Abuf;                            // [60032,1024] constr hidden
  uint16_t* featpad = Abuf + 61472768;                 // [60032,32]
  float*    featf   = (float*)(Abuf + 63393792);       // [60000,16] f32
  float*    cff     = (float*)(Abuf + 67233792);       // [60000,16] f32

  // --- init, dtype probe, edge counting-sort ---
  init_k<<<dim3(1173), 256, 0, stream>>>(deg5, modep, lossAcc);
  probe_k<<<dim3(512), 256, 0, stream>>>((const uint16_t*)feat0, modep);
  hist5_k<<<dim3(2344), 256, 0, stream>>>(dstI, etyI, deg5);
  scan1_k<<<dim3(293), 1024, 0, stream>>>(deg5, offs5, bsum);
  scan2_k<<<dim3(1), 64, 0, stream>>>(bsum);
  scan3_k<<<dim3(293), 1024, 0, stream>>>(deg5, offs5, cursor5, bsum);
  scatter5_k<<<dim3(2344), 256, 0, stream>>>(srcI, dstI, etyI, cursor5, payload);

  // --- bias / small-W conversion into bf16 arena ---
  BPack bp; int nb = 0;
  auto addB = [&](const void* s, int n, int dstoff) {
    bp.d[nb].src = s; bp.d[nb].n = n; bp.d[nb].dstoff = dstoff; ++nb;
  };
  addB(e0b1, 256, oE0B1); addB(e0b2, 256, oE0B2);
  addB(e1b1, 256, oE1B1); addB(e1b2, 256, oE1B2);
  addB(e2b1, 512, oE2B1); addB(e2b2, 256, oE2B2); addB(e2b3, 256, oE2B3);
  addB(gB, 512, oGB);
  addB(db1, 256, oDB1); addB(db2, 16, oDB2);
  addB(ceb1, 1024, oCEB1); addB(ceb2, 256, oCEB2);
  addB(cdb1, 256, oCDB1); addB(cdb2, 16, oCDB2);
  addB(dw2, 4096, oDW2); addB(cdw2, 4096, oCDW2);
  bp.n = nb;
  biasconv_k<<<dim3(16, nb), 256, 0, stream>>>(bp, arena, modep);

  // --- weight transposes (Bt layout [N][K], dual dtype) ---
  TPack tp; int nd = 0;
  auto addT = [&](const void* s, long soff, uint16_t* d, int K, int N, int Kp,
                  int dstLd, int dstOff) {
    tp.d[nd].src = s; tp.d[nd].soff = soff; tp.d[nd].dst = d;
    tp.d[nd].K = K; tp.d[nd].N = N; tp.d[nd].Kp = Kp;
    tp.d[nd].dstLd = dstLd; tp.d[nd].dstOff = dstOff; ++nd;
  };
  addT(e0w1, 0, e0w1t, 100, 256, 128, 128, 0);
  addT(e0w2, 0, e0w2t, 256, 256, 256, 256, 0);
  addT(e1w1, 0, e1w1t, 300, 256, 320, 320, 0);
  addT(e1w2, 0, e1w2t, 256, 256, 256, 256, 0);
  addT(e2w1, 0, e2w1t, 768, 512, 768, 768, 0);
  addT(e2w2, 0, e2w2t, 512, 256, 512, 512, 0);
  addT(e2w3, 0, e2w3t, 256, 256, 256, 256, 0);
  addT(dw1,  0, dw1t,  256, 256, 256, 256, 0);
  addT(cew1, 0, cew1t, 16, 1024, 32, 32, 0);
  addT(cew2, 0, cew2t, 1024, 256, 1024, 1024, 0);
  addT(cdw1, 0, cdw1t, 256, 256, 256, 256, 0);
  uint16_t* walls[2] = { wall0, wall1 };
  for (int l = 0; l < 2; ++l) {
    addT(gL, (long)l * 65536, walls[l], 256, 256, 256, KA, 0);
    for (int r = 0; r < 5; ++r)
      addT(gW, (long)(l * 5 + r) * 65536, walls[l], 256, 256, 256, KA, 256 + r * 256);
  }
  tp.n = nd;   // 23
  transpose_k<<<dim3(48, nd), 256, 0, stream>>>(tp, modep);

  // --- encoders -> h1 ---
  repack4_k<<<dim3(1024), 256, 0, stream>>>(feat0, f0p, 0, NPER, 100, 128, MP20, modep);
  gemm_bt<1><<<dim3(157, 2), 256, 0, stream>>>(f0p, 128, e0w1t, 128, arena + oE0B1, eTmp0, 256, 128);
  gemm_bt<0><<<dim3(157, 2), 256, 0, stream>>>(eTmp0, 256, e0w2t, 256, arena + oE0B2, h1, 256, 256);
  repack4_k<<<dim3(1024), 256, 0, stream>>>(feat1, f1p, 0, NPER, 300, 320, MP20, modep);
  gemm_bt<1><<<dim3(157, 2), 256, 0, stream>>>(f1p, 320, e1w1t, 320, arena + oE1B1, eTmp1, 256, 320);
  gemm_bt<0><<<dim3(157, 2), 256, 0, stream>>>(eTmp1, 256, e1w2t, 256, arena + oE1B2, h1 + (size_t)NPER * 256, 256, 256);
  repack4_k<<<dim3(2048), 256, 0, stream>>>(feat2, f2p, 0, NPER, 768, 768, MP20, modep);
  gemm_bt<1><<<dim3(157, 4), 256, 0, stream>>>(f2p, 768, e2w1t, 768, arena + oE2B1, tEnc, 512, 768);
  gemm_bt<1><<<dim3(157, 2), 256, 0, stream>>>(tEnc, 512, e2w2t, 512, arena + oE2B2, eEnc, 256, 512);
  gemm_bt<0><<<dim3(157, 2), 256, 0, stream>>>(eEnc, 256, e2w3t, 256, arena + oE2B3,
                                               h1 + (size_t)2 * NPER * 256, 256, 256);

  // --- RelGraphConv layers: one gather + one K=1536 GEMM each ---
  uint16_t* hbuf[2] = { h1, h2 };
  for (int l = 0; l < 2; ++l) {
    uint16_t* hin  = hbuf[l & 1];
    uint16_t* hout = hbuf[(l + 1) & 1];
    gather_all_k<<<dim3(15040), 256, 0, stream>>>(hin, offs5, payload, Abuf);
    gemm_bt<0><<<dim3(469, 2), 256, 0, stream>>>(Abuf, KA, walls[l], KA,
                                                 arena + oGB + l * 256, hout, 256, KA);
  }

  // --- decoder: feat = lrelu(h1@dw1+db1)@dw2 + db2 ---
  gemm_bt<1><<<dim3(469, 2), 256, 0, stream>>>(h1, 256, dw1t, 256, arena + oDB1, h2, 256, 256);
  gemv16_k<0><<<dim3(3750), 256, 0, stream>>>(h2, arena + oDW2, arena + oDB2, featf, featpad);
  zfill_k<<<dim3(4), 256, 0, stream>>>(featpad + (size_t)N_NODES * 32, 32 * 32);

  // --- constr encoder: Hc = lrelu(featpad@cew1+ceb1); h1 = Hc@cew2 + ceb2 ---
  gemm_bt<1><<<dim3(469, 8), 256, 0, stream>>>(featpad, 32, cew1t, 32, arena + oCEB1, Hc, 1024, 32);
  gemm_bt<0><<<dim3(469, 2), 256, 0, stream>>>(Hc, 1024, cew2t, 1024, arena + oCEB2, h1, 256, 1024);

  // --- constr decoder ---
  gemm_bt<1><<<dim3(469, 2), 256, 0, stream>>>(h1, 256, cdw1t, 256, arena + oCDB1, h2, 256, 256);
  gemv16_k<1><<<dim3(3750), 256, 0, stream>>>(h2, arena + oCDW2, arena + oCDB2, cff, nullptr);

  // --- outputs ---
  loss_k<<<dim3(512), 256, 0, stream>>>(cff, featf, lossAcc);
  final_k<<<dim3(1251), 256, 0, stream>>>(cff, lossAcc, modep, d_out);
}